// Round 1
// baseline (322.572 us; speedup 1.0000x reference)
//
#include <hip/hip_runtime.h>

// RoutingLayer: capsule routing on MI355X (gfx950).
// n = 50000 nodes, D=128 dims = K=8 capsules x dd=16, M=20 neighbors, max_iter=3.
// One 128-thread block per node: thread t owns (capsule kc=t>>4, dim dc=t&15).
// All neighbor capsule vectors are gathered from the RAW input and per-capsule
// normalized in-register (16-lane shfl reduce), avoiding a separate normalized
// table kernel + 50 MB of extra HBM traffic. Routing logits go through ~0.8 KB LDS.

#define D   128
#define K   8
#define DD  16
#define M   20
#define EPSN 1e-12f

__global__ __launch_bounds__(128) void routing_kernel(
    const float* __restrict__ in,      // [n, 128] raw input
    const int*   __restrict__ nbr,     // [n*20] neighbors (pre-offset)
    const int*   __restrict__ maxit_p, // [1]
    float*       __restrict__ out,     // [n, 128]
    int n)
{
    const int node = blockIdx.x;
    const int t    = threadIdx.x;      // 0..127
    const int myk  = t >> 4;           // capsule 0..7
    const int max_iter = maxit_p[0];

    __shared__ float p_lds[M][K];
    __shared__ float s_mx[M];
    __shared__ float s_inv[M];

    // ---- own x, per-capsule L2 normalize (16-lane group reduce) ----
    float xv = in[(size_t)node * D + t];
    float ss = xv * xv;
    #pragma unroll
    for (int sh = 1; sh < DD; sh <<= 1) ss += __shfl_xor(ss, sh, 64);
    xv = xv / fmaxf(sqrtf(ss), EPSN);

    // ---- gather M neighbor rows (issue all loads first, then normalize) ----
    float z[M];
    const int base = node * M;
    #pragma unroll
    for (int mm = 0; mm < M; ++mm) {
        int idx = nbr[base + mm] + node * 5;   // == target index in [0, n]
        z[mm] = ((unsigned)idx < (unsigned)n) ? in[(size_t)idx * D + t] : 0.0f;
    }
    #pragma unroll
    for (int mm = 0; mm < M; ++mm) {
        float s = z[mm] * z[mm];
        #pragma unroll
        for (int sh = 1; sh < DD; sh <<= 1) s += __shfl_xor(s, sh, 64);
        z[mm] = z[mm] / fmaxf(sqrtf(s), EPSN);   // zero row -> 0/eps = 0
    }

    // ---- iteration 0: p = softmax(0) = 1/K uniform ----
    float u = xv;
    #pragma unroll
    for (int mm = 0; mm < M; ++mm) u += z[mm] * (1.0f / (float)K);
    if (max_iter > 1) {
        float s = u * u;
        #pragma unroll
        for (int sh = 1; sh < DD; sh <<= 1) s += __shfl_xor(s, sh, 64);
        u = u / fmaxf(sqrtf(s), EPSN);
    }

    // ---- iterations 1..max_iter-1 ----
    for (int it = 1; it < max_iter; ++it) {
        // p[mm][k] = dot_dd(z[mm], u)
        #pragma unroll
        for (int mm = 0; mm < M; ++mm) {
            float pd = z[mm] * u;
            #pragma unroll
            for (int sh = 1; sh < DD; sh <<= 1) pd += __shfl_xor(pd, sh, 64);
            if ((t & (DD - 1)) == 0) p_lds[mm][myk] = pd;
        }
        __syncthreads();

        // per-m softmax stats over the K capsules (20 helper threads)
        if (t < M) {
            float mmax = p_lds[t][0];
            #pragma unroll
            for (int k = 1; k < K; ++k) mmax = fmaxf(mmax, p_lds[t][k]);
            float s = 0.0f;
            #pragma unroll
            for (int k = 0; k < K; ++k) s += __expf(p_lds[t][k] - mmax);
            s_mx[t]  = mmax;
            s_inv[t] = 1.0f / s;
        }
        __syncthreads();

        // u = sum_m z[m] * softmax_k(p)[m][myk] + x
        float unew = xv;
        #pragma unroll
        for (int mm = 0; mm < M; ++mm) {
            float wgt = __expf(p_lds[mm][myk] - s_mx[mm]) * s_inv[mm];
            unew += z[mm] * wgt;
        }
        u = unew;

        if (it < max_iter - 1) {
            float s = u * u;
            #pragma unroll
            for (int sh = 1; sh < DD; sh <<= 1) s += __shfl_xor(s, sh, 64);
            u = u / fmaxf(sqrtf(s), EPSN);
        }
        __syncthreads();   // protect p_lds before next iteration overwrites it
    }

    out[(size_t)node * D + t] = u;
}

extern "C" void kernel_launch(void* const* d_in, const int* in_sizes, int n_in,
                              void* d_out, int out_size, void* d_ws, size_t ws_size,
                              hipStream_t stream) {
    const float* in  = (const float*)d_in[0];
    const int*   nbr = (const int*)d_in[1];
    const int*   mit = (const int*)d_in[2];
    float*       out = (float*)d_out;

    const int n = in_sizes[0] / D;   // 50000

    routing_kernel<<<n, 128, 0, stream>>>(in, nbr, mit, out, n);
}

// Round 2
// 96.131 us; speedup vs baseline: 3.3555x; 3.3555x over previous
//
#include <hip/hip_runtime.h>

// RoutingLayer: capsule routing on MI355X (gfx950).
// n = 50000 nodes, D=128 = K=8 capsules x dd=16, M=20 neighbors, max_iter=3.
// Round 2: DPP-based 16-lane reductions (no shfl lane-math), prenormalized
// table in d_ws, softmax weights staged once in LDS by helper threads.

#define D   128
#define K   8
#define DD  16
#define M   20

// x + cross-lane-moved(x); ctrl must be a literal. DPP row = 16 lanes = one capsule.
#define DPPADD(x, ctrl) ((x) + __int_as_float(__builtin_amdgcn_update_dpp( \
        0, __float_as_int(x), (ctrl), 0xF, 0xF, false)))

__device__ __forceinline__ float red16(float x) {
    x = DPPADD(x, 0xB1);   // quad_perm [1,0,3,2]  : xor 1
    x = DPPADD(x, 0x4E);   // quad_perm [2,3,0,1]  : xor 2
    x = DPPADD(x, 0x141);  // row_half_mirror      : combines quads within 8
    x = DPPADD(x, 0x140);  // row_mirror           : combines halves within 16
    return x;              // all 16 lanes hold the group sum
}

__device__ __forceinline__ float norm16(float v) {
    float s = red16(v * v);
    float inv = (s > 0.0f) ? rsqrtf(s) : 0.0f;   // zero row -> 0 (matches ref 0/eps)
    return v * inv;
}

// per-capsule L2 normalize: in[n*128] -> xn[n*128]
__global__ __launch_bounds__(256) void prenorm_kernel(const float* __restrict__ in,
                                                      float* __restrict__ xn,
                                                      int total) {
    int i = blockIdx.x * 256 + threadIdx.x;
    if (i < total) xn[i] = norm16(in[i]);
}

template<bool PRENORM>
__global__ __launch_bounds__(128) void routing_kernel(
    const float* __restrict__ src,     // PRENORM ? normalized table : raw input
    const int*   __restrict__ nbr,     // [n*20]
    const int*   __restrict__ maxit_p, // [1]
    float*       __restrict__ out,     // [n, 128]
    int n)
{
    const int node = blockIdx.x;
    const int t    = threadIdx.x;      // 0..127
    const int myk  = t >> 4;           // capsule 0..7
    const int max_iter = maxit_p[0];

    __shared__ float p_lds[M][K];      // routing logits
    __shared__ float w_lds[M][K];      // softmax weights

    // own x (normalized)
    float xv = src[(size_t)node * D + t];
    if (!PRENORM) xv = norm16(xv);

    // gather M neighbor rows
    float z[M];
    const int base = node * M;
    int idxs[M];
    #pragma unroll
    for (int mm = 0; mm < M; ++mm) idxs[mm] = nbr[base + mm] + node * 5;  // uniform -> SGPR
    #pragma unroll
    for (int mm = 0; mm < M; ++mm)
        z[mm] = ((unsigned)idxs[mm] < (unsigned)n) ? src[(size_t)idxs[mm] * D + t] : 0.0f;
    if (!PRENORM) {
        #pragma unroll
        for (int mm = 0; mm < M; ++mm) z[mm] = norm16(z[mm]);
    }

    // ---- iteration 0: p = softmax(0) = 1/K ----
    float acc = 0.0f;
    #pragma unroll
    for (int mm = 0; mm < M; ++mm) acc += z[mm];
    float u = xv + 0.125f * acc;
    if (max_iter > 1) u = norm16(u);

    // ---- iterations 1..max_iter-1 ----
    for (int it = 1; it < max_iter; ++it) {
        const bool writer = ((t & 15) == 0);
        #pragma unroll
        for (int mm = 0; mm < M; ++mm) {
            float pd = red16(z[mm] * u);          // broadcast to all 16 lanes
            if (writer) p_lds[mm][myk] = pd;
        }
        __syncthreads();                           // p complete

        if (t < M) {                               // 20 helper threads do softmax once
            float4 p0 = *(const float4*)&p_lds[t][0];
            float4 p1 = *(const float4*)&p_lds[t][4];
            float mx = fmaxf(fmaxf(fmaxf(p0.x, p0.y), fmaxf(p0.z, p0.w)),
                             fmaxf(fmaxf(p1.x, p1.y), fmaxf(p1.z, p1.w)));
            float e0 = __expf(p0.x - mx), e1 = __expf(p0.y - mx);
            float e2 = __expf(p0.z - mx), e3 = __expf(p0.w - mx);
            float e4 = __expf(p1.x - mx), e5 = __expf(p1.y - mx);
            float e6 = __expf(p1.z - mx), e7 = __expf(p1.w - mx);
            float inv = 1.0f / (e0 + e1 + e2 + e3 + e4 + e5 + e6 + e7);
            *(float4*)&w_lds[t][0] = make_float4(e0 * inv, e1 * inv, e2 * inv, e3 * inv);
            *(float4*)&w_lds[t][4] = make_float4(e4 * inv, e5 * inv, e6 * inv, e7 * inv);
        }
        __syncthreads();                           // weights ready

        float unew = xv;
        #pragma unroll
        for (int mm = 0; mm < M; ++mm)
            unew += z[mm] * w_lds[mm][myk];        // LDS broadcast read, free
        u = unew;
        if (it < max_iter - 1) u = norm16(u);
        // no trailing barrier needed: next iter's p_lds writes can't pass the
        // helpers' p_lds reads (both fenced by the two barriers above), and
        // w_lds reads here complete before any thread reaches the next B1.
    }

    out[(size_t)node * D + t] = u;
}

extern "C" void kernel_launch(void* const* d_in, const int* in_sizes, int n_in,
                              void* d_out, int out_size, void* d_ws, size_t ws_size,
                              hipStream_t stream) {
    const float* in  = (const float*)d_in[0];
    const int*   nbr = (const int*)d_in[1];
    const int*   mit = (const int*)d_in[2];
    float*       out = (float*)d_out;

    const int n     = in_sizes[0] / D;    // 50000
    const int total = n * D;

    if (ws_size >= (size_t)total * sizeof(float)) {
        float* xn = (float*)d_ws;
        prenorm_kernel<<<(total + 255) / 256, 256, 0, stream>>>(in, xn, total);
        routing_kernel<true><<<n, 128, 0, stream>>>(xn, nbr, mit, out, n);
    } else {
        routing_kernel<false><<<n, 128, 0, stream>>>(in, nbr, mit, out, n);
    }
}

// Round 3
// 67.095 us; speedup vs baseline: 4.8077x; 1.4328x over previous
//
#include <hip/hip_runtime.h>

// RoutingLayer: capsule routing on MI355X (gfx950).
// n = 50000 nodes, D=128 = K=8 capsules x dd=16, M=20 neighbors, max_iter=3.
// Round 3: fp16 normalized table (halves gather bytes + L2 footprint),
// one wave per node (64 threads, 2 dims/thread), scalarized gather addresses
// via v_readlane, DPP 8-lane reductions, no __syncthreads at all.

#define D   128
#define K   8
#define DD  16
#define M   20

typedef _Float16 half2_t __attribute__((ext_vector_type(2)));

// x + dpp_moved(x); ctrl literal. DPP row = 16 lanes; half-row = 8 = one capsule here.
#define DPPADD(x, ctrl) ((x) + __int_as_float(__builtin_amdgcn_update_dpp( \
        0, __float_as_int(x), (ctrl), 0xF, 0xF, false)))

__device__ __forceinline__ float red16(float x) {   // sum over 16-lane group
    x = DPPADD(x, 0xB1);   // quad_perm [1,0,3,2]
    x = DPPADD(x, 0x4E);   // quad_perm [2,3,0,1]
    x = DPPADD(x, 0x141);  // row_half_mirror
    x = DPPADD(x, 0x140);  // row_mirror
    return x;
}
__device__ __forceinline__ float red8(float x) {    // sum over 8-lane group
    x = DPPADD(x, 0xB1);
    x = DPPADD(x, 0x4E);
    x = DPPADD(x, 0x141);
    return x;
}
__device__ __forceinline__ float2 norm2_8(float2 v) {  // capsule L2 norm, 2 dims/lane
    float s = red8(v.x * v.x + v.y * v.y);
    float inv = (s > 0.0f) ? rsqrtf(s) : 0.0f;         // zero row -> 0 (ref: 0/eps)
    v.x *= inv; v.y *= inv;
    return v;
}

// per-capsule L2 normalize into fp16 table, with zero pad row at [total, total+D)
__global__ __launch_bounds__(256) void prenorm_kernel(const float* __restrict__ in,
                                                      _Float16* __restrict__ tab,
                                                      int total) {
    int i = blockIdx.x * 256 + threadIdx.x;
    float v = (i < total) ? in[i] : 0.0f;
    float s = red16(v * v);
    float inv = (s > 0.0f) ? rsqrtf(s) : 0.0f;
    if (i < total + D) tab[i] = (_Float16)(v * inv);
}

template<bool PRE>
__global__ __launch_bounds__(256) void routing_kernel(
    const _Float16* __restrict__ tab,  // PRE: [(n+1)*128] normalized fp16, row n = 0
    const float*    __restrict__ raw,  // !PRE: raw fp32 input
    const int*      __restrict__ nbr,  // [n*20]
    const int*      __restrict__ maxit_p,
    float*          __restrict__ out,  // [n,128] fp32
    int n)
{
    const int t  = threadIdx.x;
    const int wv = t >> 6;                 // wave id = node slot in block
    const int l  = t & 63;                 // lane; owns dims (2l, 2l+1)
    const int node = blockIdx.x * 4 + wv;
    const int myk  = l >> 3;               // capsule 0..7 (8 lanes each)
    if (node >= n) return;
    const int max_iter = maxit_p[0];

    __shared__ float p_lds[4][M][K];
    __shared__ float w_lds[4][M][K];

    // neighbor ids: lane l<20 loads one; distributed to SGPRs via readlane below
    int nid_v = nbr[node * M + (l < M ? l : 0)] + node * 5;   // target in [0,n]

    // own x (2 dims)
    float2 xv;
    if (PRE) {
        const half2_t* t2 = (const half2_t*)tab;
        half2_t h = t2[(size_t)node * (D / 2) + l];
        xv.x = (float)h.x; xv.y = (float)h.y;
    } else {
        const float2* r2 = (const float2*)raw;
        xv = r2[(size_t)node * (D / 2) + l];
        xv = norm2_8(xv);
    }

    // gather M neighbor rows; scalar (SGPR) row base + shared lane offset
    float2 z[M];
    #pragma unroll
    for (int mm = 0; mm < M; ++mm) {
        int idx = __builtin_amdgcn_readlane(nid_v, mm);
        if (PRE) {
            const half2_t* t2 = (const half2_t*)tab;
            half2_t h = t2[(size_t)idx * (D / 2) + l];     // row n is zeros
            z[mm].x = (float)h.x; z[mm].y = (float)h.y;
        } else {
            if (idx < n) {
                const float2* r2 = (const float2*)raw;
                z[mm] = r2[(size_t)idx * (D / 2) + l];
            } else {
                z[mm] = make_float2(0.0f, 0.0f);
            }
        }
    }
    if (!PRE) {
        #pragma unroll
        for (int mm = 0; mm < M; ++mm) z[mm] = norm2_8(z[mm]);
    }

    // ---- iteration 0: p = softmax(0) = 1/K ----
    float sx = 0.0f, sy = 0.0f;
    #pragma unroll
    for (int mm = 0; mm < M; ++mm) { sx += z[mm].x; sy += z[mm].y; }
    float2 u = make_float2(xv.x + 0.125f * sx, xv.y + 0.125f * sy);
    if (max_iter > 1) u = norm2_8(u);

    // ---- iterations 1..max_iter-1 (all intra-wave; no __syncthreads) ----
    for (int it = 1; it < max_iter; ++it) {
        #pragma unroll
        for (int mm = 0; mm < M; ++mm) {
            float pd = red8(z[mm].x * u.x + z[mm].y * u.y);  // all 8 lanes get dot
            if ((l & 7) == 0) p_lds[wv][mm][myk] = pd;
        }
        __builtin_amdgcn_wave_barrier();   // pin LDS write -> read order

        if (l < M) {                        // 20 helper lanes: softmax over K once
            float4 p0 = *(const float4*)&p_lds[wv][l][0];
            float4 p1 = *(const float4*)&p_lds[wv][l][4];
            float mx = fmaxf(fmaxf(fmaxf(p0.x, p0.y), fmaxf(p0.z, p0.w)),
                             fmaxf(fmaxf(p1.x, p1.y), fmaxf(p1.z, p1.w)));
            float e0 = __expf(p0.x - mx), e1 = __expf(p0.y - mx);
            float e2 = __expf(p0.z - mx), e3 = __expf(p0.w - mx);
            float e4 = __expf(p1.x - mx), e5 = __expf(p1.y - mx);
            float e6 = __expf(p1.z - mx), e7 = __expf(p1.w - mx);
            float inv = 1.0f / (e0 + e1 + e2 + e3 + e4 + e5 + e6 + e7);
            *(float4*)&w_lds[wv][l][0] = make_float4(e0 * inv, e1 * inv, e2 * inv, e3 * inv);
            *(float4*)&w_lds[wv][l][4] = make_float4(e4 * inv, e5 * inv, e6 * inv, e7 * inv);
        }
        __builtin_amdgcn_wave_barrier();

        float2 unew = xv;
        #pragma unroll
        for (int mm = 0; mm < M; ++mm) {
            float w = w_lds[wv][mm][myk];   // broadcast within 8-lane group
            unew.x += z[mm].x * w;
            unew.y += z[mm].y * w;
        }
        u = unew;
        if (it < max_iter - 1) u = norm2_8(u);
        __builtin_amdgcn_wave_barrier();    // keep next iter's p writes behind w reads
    }

    float2* o2 = (float2*)out;
    o2[(size_t)node * (D / 2) + l] = u;
}

extern "C" void kernel_launch(void* const* d_in, const int* in_sizes, int n_in,
                              void* d_out, int out_size, void* d_ws, size_t ws_size,
                              hipStream_t stream) {
    const float* in  = (const float*)d_in[0];
    const int*   nbr = (const int*)d_in[1];
    const int*   mit = (const int*)d_in[2];
    float*       out = (float*)d_out;

    const int n     = in_sizes[0] / D;    // 50000
    const int total = n * D;
    const int nblk  = (n + 3) / 4;

    if (ws_size >= (size_t)(total + D) * sizeof(_Float16)) {
        _Float16* tab = (_Float16*)d_ws;
        prenorm_kernel<<<(total + D + 255) / 256, 256, 0, stream>>>(in, tab, total);
        routing_kernel<true><<<nblk, 256, 0, stream>>>(tab, nullptr, nbr, mit, out, n);
    } else {
        routing_kernel<false><<<nblk, 256, 0, stream>>>(nullptr, in, nbr, mit, out, n);
    }
}

// Round 5
// 63.229 us; speedup vs baseline: 5.1016x; 1.0611x over previous
//
#include <hip/hip_runtime.h>

// RoutingLayer: capsule routing on MI355X (gfx950).
// n = 50000 nodes, D=128 = K=8 capsules x dd=16, M=20 neighbors, max_iter=3.
// Round 5 (= round 4 + compile fix): single-inst DPP reductions (inline asm,
// 4-way interleaved for hazard distance), z kept packed f16 (v_dot2_f32_f16
// dots, v_fma_mix PV), scalar-pipe neighbor-id loads.
// Fix vs r4: bit_cast the __fp16x2 result of __builtin_amdgcn_cvt_pkrtz to h2.

#define D   128
#define K   8
#define DD  16
#define M   20

typedef _Float16 h2 __attribute__((ext_vector_type(2)));
typedef unsigned int u32;

__device__ __forceinline__ h2 pack_h2(float a, float b) {
    return __builtin_bit_cast(h2, __builtin_amdgcn_cvt_pkrtz(a, b));
}

// builtin (compiler-managed hazards) 2-inst DPP add — used in cold spots only
#define DPPADD(x, ctrl) ((x) + __int_as_float(__builtin_amdgcn_update_dpp( \
        0, __float_as_int(x), (ctrl), 0xF, 0xF, false)))

__device__ __forceinline__ float red16_b(float x) {   // sum over 16-lane group
    x = DPPADD(x, 0xB1); x = DPPADD(x, 0x4E);
    x = DPPADD(x, 0x141); x = DPPADD(x, 0x140);
    return x;
}
__device__ __forceinline__ float red8_b(float x) {    // sum over 8-lane group
    x = DPPADD(x, 0xB1); x = DPPADD(x, 0x4E); x = DPPADD(x, 0x141);
    return x;
}

// 4 independent 8-lane sum reductions, 1 inst per DPP add. Chains interleaved
// so each DPP reads a reg written >=3 insts earlier (VALU->DPP wait states);
// s_nop 1 guards chain heads against producers immediately before the block.
// volatile: convergent cross-lane op must not sink into divergent regions.
#define RED8_X4(a, b, c, d) \
  asm volatile( \
    "s_nop 1\n\t" \
    "v_add_f32_dpp %0, %0, %0 quad_perm:[1,0,3,2] row_mask:0xf bank_mask:0xf\n\t" \
    "v_add_f32_dpp %1, %1, %1 quad_perm:[1,0,3,2] row_mask:0xf bank_mask:0xf\n\t" \
    "v_add_f32_dpp %2, %2, %2 quad_perm:[1,0,3,2] row_mask:0xf bank_mask:0xf\n\t" \
    "v_add_f32_dpp %3, %3, %3 quad_perm:[1,0,3,2] row_mask:0xf bank_mask:0xf\n\t" \
    "v_add_f32_dpp %0, %0, %0 quad_perm:[2,3,0,1] row_mask:0xf bank_mask:0xf\n\t" \
    "v_add_f32_dpp %1, %1, %1 quad_perm:[2,3,0,1] row_mask:0xf bank_mask:0xf\n\t" \
    "v_add_f32_dpp %2, %2, %2 quad_perm:[2,3,0,1] row_mask:0xf bank_mask:0xf\n\t" \
    "v_add_f32_dpp %3, %3, %3 quad_perm:[2,3,0,1] row_mask:0xf bank_mask:0xf\n\t" \
    "v_add_f32_dpp %0, %0, %0 row_half_mirror row_mask:0xf bank_mask:0xf\n\t" \
    "v_add_f32_dpp %1, %1, %1 row_half_mirror row_mask:0xf bank_mask:0xf\n\t" \
    "v_add_f32_dpp %2, %2, %2 row_half_mirror row_mask:0xf bank_mask:0xf\n\t" \
    "v_add_f32_dpp %3, %3, %3 row_half_mirror row_mask:0xf bank_mask:0xf" \
    : "+v"(a), "+v"(b), "+v"(c), "+v"(d))

__device__ __forceinline__ float dot2(u32 za, h2 ub) {
#if __has_builtin(__builtin_amdgcn_fdot2)
    return __builtin_amdgcn_fdot2(__builtin_bit_cast(h2, za), ub, 0.0f, false);
#else
    h2 ah = __builtin_bit_cast(h2, za);
    return fmaf((float)ah.x, (float)ub.x, (float)ah.y * (float)ub.y);
#endif
}

// per-capsule L2 normalize into fp16 table, zero pad row at [total, total+D)
__global__ __launch_bounds__(256) void prenorm_kernel(const float* __restrict__ in,
                                                      _Float16* __restrict__ tab,
                                                      int total) {
    int i = blockIdx.x * 256 + threadIdx.x;
    float v = (i < total) ? in[i] : 0.0f;
    float s = red16_b(v * v);
    float inv = (s > 0.0f) ? rsqrtf(s) : 0.0f;
    if (i < total + D) tab[i] = (_Float16)(v * inv);
}

template<bool PRE>
__global__ __launch_bounds__(256) void routing_kernel(
    const _Float16* __restrict__ tab,  // PRE: [(n+1)*128] normalized fp16, row n = 0
    const float*    __restrict__ raw,  // !PRE: raw fp32 input
    const int*      __restrict__ nbr,  // [n*20]
    const int*      __restrict__ maxit_p,
    float*          __restrict__ out,  // [n,128] fp32
    int n)
{
    const int t  = threadIdx.x;
    const int wv = t >> 6;                 // wave slot in block
    const int l  = t & 63;                 // lane; owns dims (2l, 2l+1)
    const int node = blockIdx.x * 4 + wv;
    const int myk  = l >> 3;               // capsule 0..7 (8 lanes each)
    if (node >= n) return;
    const int max_iter = maxit_p[0];
    const int nodeu = __builtin_amdgcn_readfirstlane(node);

    __shared__ float p_lds[4][M][K];
    __shared__ float w_lds[4][M][K];

    // neighbor ids via scalar pipe (uniform address -> s_load)
    int ids[M];
    {
        const int* nrow = nbr + nodeu * M;
        #pragma unroll
        for (int mm = 0; mm < M; ++mm) ids[mm] = nrow[mm] + nodeu * 5;  // in [0,n]
    }

    // own x + gathered z rows, packed f16 pairs
    u32 z[M];
    float2 xv;
    if (PRE) {
        const u32* t32 = (const u32*)tab;
        u32 xw = t32[(size_t)nodeu * (D / 2) + l];
        h2 xh = __builtin_bit_cast(h2, xw);
        xv.x = (float)xh.x; xv.y = (float)xh.y;
        #pragma unroll
        for (int mm = 0; mm < M; ++mm)
            z[mm] = t32[(size_t)ids[mm] * (D / 2) + l];   // row n is zeros
    } else {
        const float2* r2 = (const float2*)raw;
        float2 x0 = r2[(size_t)nodeu * (D / 2) + l];
        float s = red8_b(x0.x * x0.x + x0.y * x0.y);
        float inv = (s > 0.0f) ? rsqrtf(s) : 0.0f;
        xv.x = x0.x * inv; xv.y = x0.y * inv;
        #pragma unroll
        for (int mm = 0; mm < M; ++mm) {
            float2 zv = (ids[mm] < n) ? r2[(size_t)ids[mm] * (D / 2) + l]
                                      : make_float2(0.f, 0.f);
            float s2 = red8_b(zv.x * zv.x + zv.y * zv.y);
            float i2 = (s2 > 0.0f) ? rsqrtf(s2) : 0.0f;
            z[mm] = __builtin_bit_cast(u32, pack_h2(zv.x * i2, zv.y * i2));
        }
    }

    // ---- iteration 0: p = softmax(0) = 1/K; u = x + 0.125 * sum_m z ----
    const float kEighth = 0.125f;
    float2 u = xv;
    #pragma unroll
    for (int mm = 0; mm < M; ++mm) {
        h2 zh = __builtin_bit_cast(h2, z[mm]);
        u.x = fmaf((float)zh.x, kEighth, u.x);   // v_fma_mix_f32
        u.y = fmaf((float)zh.y, kEighth, u.y);
    }
    if (max_iter > 1) {
        float s = red8_b(u.x * u.x + u.y * u.y);
        float inv = (s > 0.0f) ? rsqrtf(s) : 0.0f;
        u.x *= inv; u.y *= inv;
    }
    h2 uh = pack_h2(u.x, u.y);

    // ---- iterations 1..max_iter-1 (intra-wave only) ----
    for (int it = 1; it < max_iter; ++it) {
        #pragma unroll
        for (int mm = 0; mm < M; mm += 4) {
            float p0 = dot2(z[mm + 0], uh);
            float p1 = dot2(z[mm + 1], uh);
            float p2 = dot2(z[mm + 2], uh);
            float p3 = dot2(z[mm + 3], uh);
            RED8_X4(p0, p1, p2, p3);             // all 8 lanes hold each sum
            if ((l & 7) == 0) {
                p_lds[wv][mm + 0][myk] = p0;
                p_lds[wv][mm + 1][myk] = p1;
                p_lds[wv][mm + 2][myk] = p2;
                p_lds[wv][mm + 3][myk] = p3;
            }
        }
        __builtin_amdgcn_wave_barrier();

        if (l < M) {                              // 20 helper lanes: softmax over K
            float4 p0 = *(const float4*)&p_lds[wv][l][0];
            float4 p1 = *(const float4*)&p_lds[wv][l][4];
            float mx = fmaxf(fmaxf(fmaxf(p0.x, p0.y), fmaxf(p0.z, p0.w)),
                             fmaxf(fmaxf(p1.x, p1.y), fmaxf(p1.z, p1.w)));
            float e0 = __expf(p0.x - mx), e1 = __expf(p0.y - mx);
            float e2 = __expf(p0.z - mx), e3 = __expf(p0.w - mx);
            float e4 = __expf(p1.x - mx), e5 = __expf(p1.y - mx);
            float e6 = __expf(p1.z - mx), e7 = __expf(p1.w - mx);
            float inv = 1.0f / (e0 + e1 + e2 + e3 + e4 + e5 + e6 + e7);
            *(float4*)&w_lds[wv][l][0] = make_float4(e0 * inv, e1 * inv, e2 * inv, e3 * inv);
            *(float4*)&w_lds[wv][l][4] = make_float4(e4 * inv, e5 * inv, e6 * inv, e7 * inv);
        }
        __builtin_amdgcn_wave_barrier();

        float2 unew = xv;
        #pragma unroll
        for (int mm = 0; mm < M; ++mm) {
            float w = w_lds[wv][mm][myk];          // broadcast within 8-lane group
            h2 zh = __builtin_bit_cast(h2, z[mm]);
            unew.x = fmaf((float)zh.x, w, unew.x); // v_fma_mix_f32
            unew.y = fmaf((float)zh.y, w, unew.y);
        }
        u = unew;
        if (it < max_iter - 1) {
            float s = red8_b(u.x * u.x + u.y * u.y);
            float inv = (s > 0.0f) ? rsqrtf(s) : 0.0f;
            u.x *= inv; u.y *= inv;
        }
        uh = pack_h2(u.x, u.y);
        __builtin_amdgcn_wave_barrier();           // keep next p-writes behind w-reads
    }

    float2* o2 = (float2*)out;
    o2[(size_t)node * (D / 2) + l] = u;
}

extern "C" void kernel_launch(void* const* d_in, const int* in_sizes, int n_in,
                              void* d_out, int out_size, void* d_ws, size_t ws_size,
                              hipStream_t stream) {
    const float* in  = (const float*)d_in[0];
    const int*   nbr = (const int*)d_in[1];
    const int*   mit = (const int*)d_in[2];
    float*       out = (float*)d_out;

    const int n     = in_sizes[0] / D;    // 50000
    const int total = n * D;
    const int nblk  = (n + 3) / 4;

    if (ws_size >= (size_t)(total + D) * sizeof(_Float16)) {
        _Float16* tab = (_Float16*)d_ws;
        prenorm_kernel<<<(total + D + 255) / 256, 256, 0, stream>>>(in, tab, total);
        routing_kernel<true><<<nblk, 256, 0, stream>>>(tab, nullptr, nbr, mit, out, n);
    } else {
        routing_kernel<false><<<nblk, 256, 0, stream>>>(nullptr, in, nbr, mit, out, n);
    }
}

// Round 10
// 58.516 us; speedup vs baseline: 5.5125x; 1.0805x over previous
//
#include <hip/hip_runtime.h>

// RoutingLayer: capsule routing on MI355X (gfx950).
// n = 50000 nodes, D=128 = K=8 capsules x dd=16, M=20 neighbors, max_iter=3.
// Round 10: REVERT to the round-5 verified structure (1 node/wave, 2 dims/lane,
// LDS-staged softmax, asm RED8_X4 dot reductions), with ONE change: the
// softmax helper phase (20 serial lanes, max-tree, exact divide, stride-8
// conflicted reads) is replaced by a lane-parallel divergence-free scheme:
// lane l handles (m=base+(l>>3), k=l&7) over 3 passes; no max-sub (|p|<=1),
// e*rcp(S) instead of divide, conflict-free LDS addressing (dword l).

#define D   128
#define K   8
#define DD  16
#define M   20

typedef _Float16 h2 __attribute__((ext_vector_type(2)));
typedef unsigned int u32;

__device__ __forceinline__ h2 pack_h2(float a, float b) {
    return __builtin_bit_cast(h2, __builtin_amdgcn_cvt_pkrtz(a, b));
}

// builtin (compiler-managed hazards) DPP add
#define DPPADD(x, ctrl) ((x) + __int_as_float(__builtin_amdgcn_update_dpp( \
        0, __float_as_int(x), (ctrl), 0xF, 0xF, false)))

__device__ __forceinline__ float red16_b(float x) {   // sum over 16-lane group
    x = DPPADD(x, 0xB1); x = DPPADD(x, 0x4E);
    x = DPPADD(x, 0x141); x = DPPADD(x, 0x140);
    return x;
}
__device__ __forceinline__ float red8_b(float x) {    // sum over 8-lane group
    x = DPPADD(x, 0xB1); x = DPPADD(x, 0x4E); x = DPPADD(x, 0x141);
    return x;
}

// 4 independent 8-lane sum reductions, 1 inst per DPP add (r5-proven).
#define RED8_X4(a, b, c, d) \
  asm volatile( \
    "s_nop 1\n\t" \
    "v_add_f32_dpp %0, %0, %0 quad_perm:[1,0,3,2] row_mask:0xf bank_mask:0xf\n\t" \
    "v_add_f32_dpp %1, %1, %1 quad_perm:[1,0,3,2] row_mask:0xf bank_mask:0xf\n\t" \
    "v_add_f32_dpp %2, %2, %2 quad_perm:[1,0,3,2] row_mask:0xf bank_mask:0xf\n\t" \
    "v_add_f32_dpp %3, %3, %3 quad_perm:[1,0,3,2] row_mask:0xf bank_mask:0xf\n\t" \
    "v_add_f32_dpp %0, %0, %0 quad_perm:[2,3,0,1] row_mask:0xf bank_mask:0xf\n\t" \
    "v_add_f32_dpp %1, %1, %1 quad_perm:[2,3,0,1] row_mask:0xf bank_mask:0xf\n\t" \
    "v_add_f32_dpp %2, %2, %2 quad_perm:[2,3,0,1] row_mask:0xf bank_mask:0xf\n\t" \
    "v_add_f32_dpp %3, %3, %3 quad_perm:[2,3,0,1] row_mask:0xf bank_mask:0xf\n\t" \
    "v_add_f32_dpp %0, %0, %0 row_half_mirror row_mask:0xf bank_mask:0xf\n\t" \
    "v_add_f32_dpp %1, %1, %1 row_half_mirror row_mask:0xf bank_mask:0xf\n\t" \
    "v_add_f32_dpp %2, %2, %2 row_half_mirror row_mask:0xf bank_mask:0xf\n\t" \
    "v_add_f32_dpp %3, %3, %3 row_half_mirror row_mask:0xf bank_mask:0xf" \
    : "+v"(a), "+v"(b), "+v"(c), "+v"(d))

__device__ __forceinline__ float dot2(u32 za, h2 ub) {
#if __has_builtin(__builtin_amdgcn_fdot2)
    return __builtin_amdgcn_fdot2(__builtin_bit_cast(h2, za), ub, 0.0f, false);
#else
    h2 ah = __builtin_bit_cast(h2, za);
    return fmaf((float)ah.x, (float)ub.x, (float)ah.y * (float)ub.y);
#endif
}

// per-capsule L2 normalize into fp16 table, zero pad row at [total, total+D)
__global__ __launch_bounds__(256) void prenorm_kernel(const float* __restrict__ in,
                                                      _Float16* __restrict__ tab,
                                                      int total) {
    int i = blockIdx.x * 256 + threadIdx.x;
    float v = (i < total) ? in[i] : 0.0f;
    float s = red16_b(v * v);
    float inv = (s > 0.0f) ? rsqrtf(s) : 0.0f;
    if (i < total + D) tab[i] = (_Float16)(v * inv);
}

template<bool PRE>
__global__ __launch_bounds__(256) void routing_kernel(
    const _Float16* __restrict__ tab,  // PRE: [(n+1)*128] normalized fp16, row n = 0
    const float*    __restrict__ raw,  // !PRE: raw fp32 input
    const int*      __restrict__ nbr,  // [n*20]
    const int*      __restrict__ maxit_p,
    float*          __restrict__ out,  // [n,128] fp32
    int n)
{
    const int t  = threadIdx.x;
    const int wv = t >> 6;                 // wave slot in block
    const int l  = t & 63;                 // lane; owns dims (2l, 2l+1)
    const int node = blockIdx.x * 4 + wv;
    const int myk  = l >> 3;               // capsule 0..7 (8 lanes each)
    if (node >= n) return;
    const int max_iter = maxit_p[0];
    const int nodeu = __builtin_amdgcn_readfirstlane(node);

    __shared__ float p_lds[4][M][K];
    __shared__ float w_lds[4][M][K];

    // neighbor ids via scalar pipe (uniform address -> s_load)
    int ids[M];
    {
        const int* nrow = nbr + nodeu * M;
        #pragma unroll
        for (int mm = 0; mm < M; ++mm) ids[mm] = nrow[mm] + nodeu * 5;  // in [0,n]
    }

    // own x + gathered z rows, packed f16 pairs
    u32 z[M];
    float2 xv;
    if (PRE) {
        const u32* t32 = (const u32*)tab;
        u32 xw = t32[(size_t)nodeu * (D / 2) + l];
        h2 xh = __builtin_bit_cast(h2, xw);
        xv.x = (float)xh.x; xv.y = (float)xh.y;
        #pragma unroll
        for (int mm = 0; mm < M; ++mm)
            z[mm] = t32[(size_t)ids[mm] * (D / 2) + l];   // row n is zeros
    } else {
        const float2* r2 = (const float2*)raw;
        float2 x0 = r2[(size_t)nodeu * (D / 2) + l];
        float s = red8_b(x0.x * x0.x + x0.y * x0.y);
        float inv = (s > 0.0f) ? rsqrtf(s) : 0.0f;
        xv.x = x0.x * inv; xv.y = x0.y * inv;
        #pragma unroll
        for (int mm = 0; mm < M; ++mm) {
            float2 zv = (ids[mm] < n) ? r2[(size_t)ids[mm] * (D / 2) + l]
                                      : make_float2(0.f, 0.f);
            float s2 = red8_b(zv.x * zv.x + zv.y * zv.y);
            float i2 = (s2 > 0.0f) ? rsqrtf(s2) : 0.0f;
            z[mm] = __builtin_bit_cast(u32, pack_h2(zv.x * i2, zv.y * i2));
        }
    }

    // ---- iteration 0: p = softmax(0) = 1/K; u = x + 0.125 * sum_m z ----
    const float kEighth = 0.125f;
    float2 u = xv;
    #pragma unroll
    for (int mm = 0; mm < M; ++mm) {
        h2 zh = __builtin_bit_cast(h2, z[mm]);
        u.x = fmaf((float)zh.x, kEighth, u.x);   // v_fma_mix_f32
        u.y = fmaf((float)zh.y, kEighth, u.y);
    }
    if (max_iter > 1) {
        float s = red8_b(u.x * u.x + u.y * u.y);
        float inv = (s > 0.0f) ? rsqrtf(s) : 0.0f;
        u.x *= inv; u.y *= inv;
    }
    h2 uh = pack_h2(u.x, u.y);

    // ---- iterations 1..max_iter-1 (intra-wave only) ----
    for (int it = 1; it < max_iter; ++it) {
        // phase 1: capsule dots -> p_lds (r5-proven)
        #pragma unroll
        for (int mm = 0; mm < M; mm += 4) {
            float p0 = dot2(z[mm + 0], uh);
            float p1 = dot2(z[mm + 1], uh);
            float p2 = dot2(z[mm + 2], uh);
            float p3 = dot2(z[mm + 3], uh);
            RED8_X4(p0, p1, p2, p3);             // all 8 lanes hold each sum
            if ((l & 7) == 0) {
                p_lds[wv][mm + 0][myk] = p0;
                p_lds[wv][mm + 1][myk] = p1;
                p_lds[wv][mm + 2][myk] = p2;
                p_lds[wv][mm + 3][myk] = p3;
            }
        }
        __builtin_amdgcn_wave_barrier();

        // phase 2 (NEW): lane-parallel softmax, no divergence.
        // Lane l handles (m = base + (l>>3), k = l&7); 3 passes (8,8,4 m's).
        // |p| <= 1 (unit vectors) -> skip max subtraction. S via proven red8_b.
        // LDS dword offset = base*8 + l -> fully conflict-free read & write.
        #pragma unroll
        for (int base = 0; base < M; base += 8) {
            int mm = base + (l >> 3);
            int mc = (mm < M) ? mm : (M - 1);          // clamp: keeps all lanes live
            float e = __expf(p_lds[wv][mc][l & 7]);
            float S = red8_b(e);                        // sum over k within 8-group
            float w = e * __builtin_amdgcn_rcpf(S);
            if (mm < M) w_lds[wv][mm][l & 7] = w;
        }
        __builtin_amdgcn_wave_barrier();

        // phase 3: PV accumulate
        float2 unew = xv;
        #pragma unroll
        for (int mm = 0; mm < M; ++mm) {
            float w = w_lds[wv][mm][myk];          // broadcast within 8-lane group
            h2 zh = __builtin_bit_cast(h2, z[mm]);
            unew.x = fmaf((float)zh.x, w, unew.x); // v_fma_mix_f32
            unew.y = fmaf((float)zh.y, w, unew.y);
        }
        u = unew;
        if (it < max_iter - 1) {
            float s = red8_b(u.x * u.x + u.y * u.y);
            float inv = (s > 0.0f) ? rsqrtf(s) : 0.0f;
            u.x *= inv; u.y *= inv;
        }
        uh = pack_h2(u.x, u.y);
        __builtin_amdgcn_wave_barrier();           // keep next p-writes behind w-reads
    }

    float2* o2 = (float2*)out;
    o2[(size_t)node * (D / 2) + l] = u;
}

extern "C" void kernel_launch(void* const* d_in, const int* in_sizes, int n_in,
                              void* d_out, int out_size, void* d_ws, size_t ws_size,
                              hipStream_t stream) {
    const float* in  = (const float*)d_in[0];
    const int*   nbr = (const int*)d_in[1];
    const int*   mit = (const int*)d_in[2];
    float*       out = (float*)d_out;

    const int n     = in_sizes[0] / D;    // 50000
    const int total = n * D;
    const int nblk  = (n + 3) / 4;

    if (ws_size >= (size_t)(total + D) * sizeof(_Float16)) {
        _Float16* tab = (_Float16*)d_ws;
        prenorm_kernel<<<(total + D + 255) / 256, 256, 0, stream>>>(in, tab, total);
        routing_kernel<true><<<nblk, 256, 0, stream>>>(tab, nullptr, nbr, mit, out, n);
    } else {
        routing_kernel<false><<<nblk, 256, 0, stream>>>(nullptr, in, nbr, mit, out, n);
    }
}

// Round 11
// 53.434 us; speedup vs baseline: 6.0368x; 1.0951x over previous
//
#include <hip/hip_runtime.h>

// RoutingLayer: capsule routing on MI355X (gfx950).
// n = 50000 nodes, D=128 = K=8 capsules x dd=16, M=20 neighbors, max_iter=3.
// Round 11 = round 10 (verified) + packed-f16 accumulation:
//  - u kept as packed h2 end-to-end; iter0/PV use v_pk_fma_f16 (2 dims/inst,
//    was 2x v_fma_mix), weights stored PRE-PACKED (h2{w,w}) in w_lds,
//    u-norm sum-of-squares via dot2(u,u), no per-iter cvt_pkrtz repack.
// Everything else (dots, RED8_X4, lane-parallel softmax, addressing) is
// byte-identical to the round-10 verified kernel.

#define D   128
#define K   8
#define DD  16
#define M   20

typedef _Float16 h2 __attribute__((ext_vector_type(2)));
typedef unsigned int u32;

__device__ __forceinline__ h2 pack_h2(float a, float b) {
    return __builtin_bit_cast(h2, __builtin_amdgcn_cvt_pkrtz(a, b));
}

// builtin (compiler-managed hazards) DPP add
#define DPPADD(x, ctrl) ((x) + __int_as_float(__builtin_amdgcn_update_dpp( \
        0, __float_as_int(x), (ctrl), 0xF, 0xF, false)))

__device__ __forceinline__ float red16_b(float x) {   // sum over 16-lane group
    x = DPPADD(x, 0xB1); x = DPPADD(x, 0x4E);
    x = DPPADD(x, 0x141); x = DPPADD(x, 0x140);
    return x;
}
__device__ __forceinline__ float red8_b(float x) {    // sum over 8-lane group
    x = DPPADD(x, 0xB1); x = DPPADD(x, 0x4E); x = DPPADD(x, 0x141);
    return x;
}

// 4 independent 8-lane sum reductions, 1 inst per DPP add (r5/r10-proven).
#define RED8_X4(a, b, c, d) \
  asm volatile( \
    "s_nop 1\n\t" \
    "v_add_f32_dpp %0, %0, %0 quad_perm:[1,0,3,2] row_mask:0xf bank_mask:0xf\n\t" \
    "v_add_f32_dpp %1, %1, %1 quad_perm:[1,0,3,2] row_mask:0xf bank_mask:0xf\n\t" \
    "v_add_f32_dpp %2, %2, %2 quad_perm:[1,0,3,2] row_mask:0xf bank_mask:0xf\n\t" \
    "v_add_f32_dpp %3, %3, %3 quad_perm:[1,0,3,2] row_mask:0xf bank_mask:0xf\n\t" \
    "v_add_f32_dpp %0, %0, %0 quad_perm:[2,3,0,1] row_mask:0xf bank_mask:0xf\n\t" \
    "v_add_f32_dpp %1, %1, %1 quad_perm:[2,3,0,1] row_mask:0xf bank_mask:0xf\n\t" \
    "v_add_f32_dpp %2, %2, %2 quad_perm:[2,3,0,1] row_mask:0xf bank_mask:0xf\n\t" \
    "v_add_f32_dpp %3, %3, %3 quad_perm:[2,3,0,1] row_mask:0xf bank_mask:0xf\n\t" \
    "v_add_f32_dpp %0, %0, %0 row_half_mirror row_mask:0xf bank_mask:0xf\n\t" \
    "v_add_f32_dpp %1, %1, %1 row_half_mirror row_mask:0xf bank_mask:0xf\n\t" \
    "v_add_f32_dpp %2, %2, %2 row_half_mirror row_mask:0xf bank_mask:0xf\n\t" \
    "v_add_f32_dpp %3, %3, %3 row_half_mirror row_mask:0xf bank_mask:0xf" \
    : "+v"(a), "+v"(b), "+v"(c), "+v"(d))

__device__ __forceinline__ float dot2(u32 za, h2 ub) {
#if __has_builtin(__builtin_amdgcn_fdot2)
    return __builtin_amdgcn_fdot2(__builtin_bit_cast(h2, za), ub, 0.0f, false);
#else
    h2 ah = __builtin_bit_cast(h2, za);
    return fmaf((float)ah.x, (float)ub.x, (float)ah.y * (float)ub.y);
#endif
}

// per-capsule L2 normalize into fp16 table, zero pad row at [total, total+D)
__global__ __launch_bounds__(256) void prenorm_kernel(const float* __restrict__ in,
                                                      _Float16* __restrict__ tab,
                                                      int total) {
    int i = blockIdx.x * 256 + threadIdx.x;
    float v = (i < total) ? in[i] : 0.0f;
    float s = red16_b(v * v);
    float inv = (s > 0.0f) ? rsqrtf(s) : 0.0f;
    if (i < total + D) tab[i] = (_Float16)(v * inv);
}

template<bool PRE>
__global__ __launch_bounds__(256) void routing_kernel(
    const _Float16* __restrict__ tab,  // PRE: [(n+1)*128] normalized fp16, row n = 0
    const float*    __restrict__ raw,  // !PRE: raw fp32 input
    const int*      __restrict__ nbr,  // [n*20]
    const int*      __restrict__ maxit_p,
    float*          __restrict__ out,  // [n,128] fp32
    int n)
{
    const int t  = threadIdx.x;
    const int wv = t >> 6;                 // wave slot in block
    const int l  = t & 63;                 // lane; owns dims (2l, 2l+1)
    const int node = blockIdx.x * 4 + wv;
    const int myk  = l >> 3;               // capsule 0..7 (8 lanes each)
    if (node >= n) return;
    const int max_iter = maxit_p[0];
    const int nodeu = __builtin_amdgcn_readfirstlane(node);

    __shared__ float p_lds[4][M][K];       // logits (f32)
    __shared__ u32   w_lds[4][M][K];       // packed h2{w,w} weights

    // neighbor ids via scalar pipe (uniform address -> s_load)
    int ids[M];
    {
        const int* nrow = nbr + nodeu * M;
        #pragma unroll
        for (int mm = 0; mm < M; ++mm) ids[mm] = nrow[mm] + nodeu * 5;  // in [0,n]
    }

    // own x + gathered z rows, packed f16 pairs
    u32 z[M];
    h2  xh;                                // own normalized x, packed f16
    if (PRE) {
        const u32* t32 = (const u32*)tab;
        xh = __builtin_bit_cast(h2, t32[(size_t)nodeu * (D / 2) + l]);
        #pragma unroll
        for (int mm = 0; mm < M; ++mm)
            z[mm] = t32[(size_t)ids[mm] * (D / 2) + l];   // row n is zeros
    } else {
        const float2* r2 = (const float2*)raw;
        float2 x0 = r2[(size_t)nodeu * (D / 2) + l];
        float s = red8_b(x0.x * x0.x + x0.y * x0.y);
        float inv = (s > 0.0f) ? rsqrtf(s) : 0.0f;
        xh = pack_h2(x0.x * inv, x0.y * inv);
        #pragma unroll
        for (int mm = 0; mm < M; ++mm) {
            float2 zv = (ids[mm] < n) ? r2[(size_t)ids[mm] * (D / 2) + l]
                                      : make_float2(0.f, 0.f);
            float s2 = red8_b(zv.x * zv.x + zv.y * zv.y);
            float i2 = (s2 > 0.0f) ? rsqrtf(s2) : 0.0f;
            z[mm] = __builtin_bit_cast(u32, pack_h2(zv.x * i2, zv.y * i2));
        }
    }

    // ---- iteration 0: p = softmax(0) = 1/K; u = x + 0.125 * sum_m z ----
    const h2 kEighth = pack_h2(0.125f, 0.125f);
    h2 u = xh;
    #pragma unroll
    for (int mm = 0; mm < M; ++mm)
        u = __builtin_bit_cast(h2, z[mm]) * kEighth + u;   // v_pk_fma_f16
    if (max_iter > 1) {
        float s = red8_b(dot2(__builtin_bit_cast(u32, u), u));  // sum u^2 over capsule
        float inv = (s > 0.0f) ? rsqrtf(s) : 0.0f;
        h2 invh = pack_h2(inv, inv);
        u = u * invh;                                      // v_pk_mul_f16
    }

    // ---- iterations 1..max_iter-1 (intra-wave only) ----
    for (int it = 1; it < max_iter; ++it) {
        // phase 1: capsule dots -> p_lds (r5/r10-proven)
        #pragma unroll
        for (int mm = 0; mm < M; mm += 4) {
            float p0 = dot2(z[mm + 0], u);
            float p1 = dot2(z[mm + 1], u);
            float p2 = dot2(z[mm + 2], u);
            float p3 = dot2(z[mm + 3], u);
            RED8_X4(p0, p1, p2, p3);             // all 8 lanes hold each sum
            if ((l & 7) == 0) {
                p_lds[wv][mm + 0][myk] = p0;
                p_lds[wv][mm + 1][myk] = p1;
                p_lds[wv][mm + 2][myk] = p2;
                p_lds[wv][mm + 3][myk] = p3;
            }
        }
        __builtin_amdgcn_wave_barrier();

        // phase 2: lane-parallel softmax (r10-proven), now storing packed h2{w,w}.
        // Lane l handles (m = base + (l>>3), k = l&7); 3 passes; no max-sub
        // (|p|<=1 for unit vectors); S via red8_b; w = e * rcp(S).
        #pragma unroll
        for (int base = 0; base < M; base += 8) {
            int mm = base + (l >> 3);
            int mc = (mm < M) ? mm : (M - 1);          // clamp keeps all lanes live
            float e = __expf(p_lds[wv][mc][l & 7]);
            float S = red8_b(e);                        // sum over k within 8-group
            float w = e * __builtin_amdgcn_rcpf(S);
            if (mm < M)
                w_lds[wv][mm][l & 7] = __builtin_bit_cast(u32, pack_h2(w, w));
        }
        __builtin_amdgcn_wave_barrier();

        // phase 3: PV accumulate, packed f16 (1 v_pk_fma_f16 per m)
        h2 unew = xh;
        #pragma unroll
        for (int mm = 0; mm < M; ++mm) {
            h2 w2 = __builtin_bit_cast(h2, w_lds[wv][mm][myk]);
            unew = __builtin_bit_cast(h2, z[mm]) * w2 + unew;
        }
        u = unew;
        if (it < max_iter - 1) {
            float s = red8_b(dot2(__builtin_bit_cast(u32, u), u));
            float inv = (s > 0.0f) ? rsqrtf(s) : 0.0f;
            h2 invh = pack_h2(inv, inv);
            u = u * invh;
        }
        __builtin_amdgcn_wave_barrier();           // keep next p-writes behind w-reads
    }

    // ---- store: unpack h2 -> f32 pair, coalesced float2 ----
    float2* o2 = (float2*)out;
    o2[(size_t)node * (D / 2) + l] = make_float2((float)u.x, (float)u.y);
}

extern "C" void kernel_launch(void* const* d_in, const int* in_sizes, int n_in,
                              void* d_out, int out_size, void* d_ws, size_t ws_size,
                              hipStream_t stream) {
    const float* in  = (const float*)d_in[0];
    const int*   nbr = (const int*)d_in[1];
    const int*   mit = (const int*)d_in[2];
    float*       out = (float*)d_out;

    const int n     = in_sizes[0] / D;    // 50000
    const int total = n * D;
    const int nblk  = (n + 3) / 4;

    if (ws_size >= (size_t)(total + D) * sizeof(_Float16)) {
        _Float16* tab = (_Float16*)d_ws;
        prenorm_kernel<<<(total + D + 255) / 256, 256, 0, stream>>>(in, tab, total);
        routing_kernel<true><<<nblk, 256, 0, stream>>>(tab, nullptr, nbr, mit, out, n);
    } else {
        routing_kernel<false><<<nblk, 256, 0, stream>>>(nullptr, in, nbr, mit, out, n);
    }
}